// Round 1
// baseline (4136.263 us; speedup 1.0000x reference)
//
#include <hip/hip_runtime.h>
#include <math.h>

#define NB 8
#define NN 10000
#define NT 12
#define ND 16
#define NH 128
#define NE 160000
#define BN (NB * NN)  // 80000

__device__ __forceinline__ float sigmoidf_(float x) {
    return 1.0f / (1.0f + __expf(-x));
}
__device__ __forceinline__ float tanh_fast(float x) {
    x = fminf(15.0f, fmaxf(-15.0f, x));
    float t = __expf(-2.0f * x);
    return (1.0f - t) / (1.0f + t);
}

// ---------------- LSTM: 64 sequences per block, h double-buffered in LDS ----
__global__ __launch_bounds__(256, 2) void lstm_k(
    const float* __restrict__ x, const float* __restrict__ Wih,
    const float* __restrict__ Whh, const float* __restrict__ bih,
    const float* __restrict__ bhh, float* __restrict__ hout)
{
    __shared__ float hbuf[2][64][129];   // stride 129: (s+k)%32 banks, 2-way = free
    __shared__ float xbuf[64][17];
    const int tid = threadIdx.x;
    const int s = tid & 63;
    const int cg = __builtin_amdgcn_readfirstlane(tid >> 6);  // wave-uniform 0..3
    const long seq0 = (long)blockIdx.x * 64;

    for (int l = tid; l < 2 * 64 * 129; l += 256) ((float*)hbuf)[l] = 0.0f;
    float c[32];
#pragma unroll
    for (int i = 0; i < 32; ++i) c[i] = 0.0f;
    __syncthreads();

    for (int t = 0; t < NT; ++t) {
        for (int l = tid; l < 64 * ND; l += 256) {
            int ls = l >> 4, ld = l & 15;
            xbuf[ls][ld] = x[(seq0 + ls) * (NT * ND) + t * ND + ld];
        }
        __syncthreads();
        const int cur = t & 1, nxt = cur ^ 1;
        const float* __restrict__ hrow = &hbuf[cur][s][0];
#pragma unroll
        for (int jq = 0; jq < 8; ++jq) {          // unrolled so c[] indices are static
            const int j0 = cg * 32 + jq * 4;
            float acc[16];
#pragma unroll
            for (int g = 0; g < 4; ++g)
#pragma unroll
                for (int jj = 0; jj < 4; ++jj) {
                    int row = g * NH + j0 + jj;
                    acc[g * 4 + jj] = bih[row] + bhh[row];   // scalar loads
                }
#pragma unroll 4
            for (int d = 0; d < ND; ++d) {
                float xv = xbuf[s][d];
#pragma unroll
                for (int g = 0; g < 4; ++g)
#pragma unroll
                    for (int jj = 0; jj < 4; ++jj)
                        acc[g * 4 + jj] = fmaf(Wih[(g * NH + j0 + jj) * ND + d], xv, acc[g * 4 + jj]);
            }
#pragma unroll 4
            for (int k = 0; k < NH; ++k) {
                float hv = hrow[k];
#pragma unroll
                for (int g = 0; g < 4; ++g)
#pragma unroll
                    for (int jj = 0; jj < 4; ++jj)
                        acc[g * 4 + jj] = fmaf(Whh[(g * NH + j0 + jj) * NH + k], hv, acc[g * 4 + jj]);
            }
#pragma unroll
            for (int jj = 0; jj < 4; ++jj) {
                float iv = sigmoidf_(acc[0 + jj]);
                float fv = sigmoidf_(acc[4 + jj]);
                float gv = tanh_fast(acc[8 + jj]);
                float ov = sigmoidf_(acc[12 + jj]);
                float cc = fv * c[jq * 4 + jj] + iv * gv;
                c[jq * 4 + jj] = cc;
                hbuf[nxt][s][j0 + jj] = ov * tanh_fast(cc);
            }
        }
        __syncthreads();
    }
    // 12 steps (even) -> final h is in buffer 0
    for (int l = tid; l < 64 * NH; l += 256) {
        int ls = l >> 7, lj = l & 127;
        hout[(seq0 + ls) * NH + lj] = hbuf[0][ls][lj];
    }
}

// ---------------- degree / CSR build ----------------------------------------
__global__ void init_k(float* deg, int* cnt, int* fill) {
    int n = blockIdx.x * 256 + threadIdx.x;
    if (n < NN) { deg[n] = 1.0f; cnt[n] = 0; fill[n] = 0; }  // 1.0 = self-loop
}

__global__ void degacc_k(const int* __restrict__ ei, const float* __restrict__ ew,
                         float* deg, int* cnt) {
    int e = blockIdx.x * 256 + threadIdx.x;
    if (e < NE) {
        int d = ei[NE + e];
        atomicAdd(&deg[d], ew[e]);
        atomicAdd(&cnt[d], 1);
    }
}

__global__ void dinv_k(const float* __restrict__ deg, float* dinv) {
    int n = blockIdx.x * 256 + threadIdx.x;
    if (n < NN) { float d = deg[n]; dinv[n] = d > 0.0f ? 1.0f / sqrtf(d) : 0.0f; }
}

__global__ __launch_bounds__(1024) void scan_k(const int* __restrict__ cnt,
                                               int* __restrict__ rowp) {
    __shared__ int sA[1024];
    __shared__ int sB[1024];
    const int tid = threadIdx.x;
    const int CH = 10;  // 1024*10 >= 10000
    int base = tid * CH;
    int local[CH];
    int ssum = 0;
#pragma unroll
    for (int i = 0; i < CH; ++i) {
        int idx = base + i;
        int v = (idx < NN) ? cnt[idx] : 0;
        local[i] = v; ssum += v;
    }
    int* src = sA; int* dst = sB;
    src[tid] = ssum;
    __syncthreads();
    for (int off = 1; off < 1024; off <<= 1) {
        int v = src[tid];
        if (tid >= off) v += src[tid - off];
        dst[tid] = v;
        __syncthreads();
        int* tmp = src; src = dst; dst = tmp;
    }
    int run = src[tid] - ssum;  // exclusive prefix
#pragma unroll
    for (int i = 0; i < CH; ++i) {
        int idx = base + i;
        if (idx < NN) rowp[idx] = run;
        run += local[i];
    }
    if (tid == 1023) rowp[NN] = src[1023];
}

__global__ void scatter_k(const int* __restrict__ ei, const float* __restrict__ ew,
                          const float* __restrict__ dinv, const int* __restrict__ rowp,
                          int* fill, int* __restrict__ col, float* __restrict__ val)
{
    int e = blockIdx.x * 256 + threadIdx.x;
    if (e >= NE) return;
    int srcn = ei[e], d = ei[NE + e];
    int pos = rowp[d] + atomicAdd(&fill[d], 1);
    col[pos] = srcn;
    val[pos] = dinv[srcn] * ew[e] * dinv[d];
}

// ---------------- xl = h @ W^T  (W: (128,128) row-major) --------------------
__global__ __launch_bounds__(256) void gemm_k(const float* __restrict__ in,
                                              const float* __restrict__ W,
                                              float* __restrict__ out)
{
    __shared__ float Wl[128 * 132];
    __shared__ float hl[8][132];
    const int tid = threadIdx.x;
    for (int l = tid; l < 128 * 32; l += 256) {
        int j = l >> 5, k4 = l & 31;
        float4 w4 = ((const float4*)W)[l];
        *(float4*)&Wl[j * 132 + k4 * 4] = w4;
    }
    const int rl = tid >> 5;   // 0..7
    const int jg = tid & 31;   // 0..31
    for (int it = 0; it < 4; ++it) {
        const long row0 = (long)blockIdx.x * 32 + it * 8;
        __syncthreads();  // previous-iter readers done (and no-op first time)
        for (int l = tid; l < 8 * 32; l += 256) {
            int r = l >> 5, k4 = l & 31;
            *(float4*)&hl[r][k4 * 4] = ((const float4*)(in + (row0 + r) * NH))[k4];
        }
        __syncthreads();
        float a0 = 0, a1 = 0, a2 = 0, a3 = 0;
#pragma unroll 4
        for (int k4 = 0; k4 < 32; ++k4) {
            float4 hv = *(const float4*)&hl[rl][k4 * 4];
            float4 w0 = *(const float4*)&Wl[(jg) * 132 + k4 * 4];
            float4 w1 = *(const float4*)&Wl[(jg + 32) * 132 + k4 * 4];
            float4 w2 = *(const float4*)&Wl[(jg + 64) * 132 + k4 * 4];
            float4 w3 = *(const float4*)&Wl[(jg + 96) * 132 + k4 * 4];
            a0 = fmaf(w0.x, hv.x, a0); a0 = fmaf(w0.y, hv.y, a0);
            a0 = fmaf(w0.z, hv.z, a0); a0 = fmaf(w0.w, hv.w, a0);
            a1 = fmaf(w1.x, hv.x, a1); a1 = fmaf(w1.y, hv.y, a1);
            a1 = fmaf(w1.z, hv.z, a1); a1 = fmaf(w1.w, hv.w, a1);
            a2 = fmaf(w2.x, hv.x, a2); a2 = fmaf(w2.y, hv.y, a2);
            a2 = fmaf(w2.z, hv.z, a2); a2 = fmaf(w2.w, hv.w, a2);
            a3 = fmaf(w3.x, hv.x, a3); a3 = fmaf(w3.y, hv.y, a3);
            a3 = fmaf(w3.z, hv.z, a3); a3 = fmaf(w3.w, hv.w, a3);
        }
        float* orow = out + (row0 + rl) * NH;
        orow[jg] = a0; orow[jg + 32] = a1; orow[jg + 64] = a2; orow[jg + 96] = a3;
    }
}

// ---------------- gather-aggregate + bias + relu (one wave per (b,dst)) -----
__global__ __launch_bounds__(256) void gather_k(const float* __restrict__ xl,
    const int* __restrict__ rowp, const int* __restrict__ col,
    const float* __restrict__ val, const float* __restrict__ dinv,
    const float* __restrict__ bias, float* __restrict__ out)
{
    const int lane = threadIdx.x & 63;
    const int wv = threadIdx.x >> 6;
    const int p = blockIdx.x * 4 + wv;   // 0..79999
    const int b = p / NN;
    const int n = p - b * NN;
    const float* __restrict__ xb = xl + (long)b * NN * NH;
    const float dn = dinv[n];
    float2 acc = ((const float2*)(xb + (long)n * NH))[lane];
    const float sn = dn * dn;            // self-loop norm
    acc.x *= sn; acc.y *= sn;
    const int e1 = rowp[n + 1];
    for (int e = rowp[n]; e < e1; ++e) {  // e, col[e], val[e] wave-uniform -> scalar
        const int sidx = col[e];
        const float w = val[e];
        const float2 u = ((const float2*)(xb + (long)sidx * NH))[lane];
        acc.x = fmaf(w, u.x, acc.x);
        acc.y = fmaf(w, u.y, acc.y);
    }
    const float bx = bias[2 * lane], by = bias[2 * lane + 1];
    const float ox = fmaxf(acc.x + bx, 0.0f);
    const float oy = fmaxf(acc.y + by, 0.0f);
    ((float2*)(out + (long)p * NH))[lane] = make_float2(ox, oy);
}

// ---------------- final FC: 128 -> 16 ---------------------------------------
__global__ __launch_bounds__(256) void fc_k(const float* __restrict__ h,
    const float* __restrict__ fw, const float* __restrict__ fb,
    float* __restrict__ out)
{
    __shared__ float wl[16][129];
    __shared__ float hl[16][129];
    const int tid = threadIdx.x;
    for (int l = tid; l < 16 * 128; l += 256) wl[l >> 7][l & 127] = fw[l];
    const long r0 = (long)blockIdx.x * 16;
    for (int l = tid; l < 16 * 128; l += 256) hl[l >> 7][l & 127] = h[r0 * NH + l];
    __syncthreads();
    const int rl = tid >> 4, o = tid & 15;
    float acc = fb[o];
#pragma unroll 8
    for (int k = 0; k < NH; ++k) acc = fmaf(hl[rl][k], wl[o][k], acc);
    out[(r0 + rl) * 16 + o] = acc;
}

// ---------------------------------------------------------------------------
extern "C" void kernel_launch(void* const* d_in, const int* in_sizes, int n_in,
                              void* d_out, int out_size, void* d_ws, size_t ws_size,
                              hipStream_t stream)
{
    const float* x   = (const float*)d_in[0];
    const int*   ei  = (const int*)d_in[1];
    const float* ew  = (const float*)d_in[2];
    const float* Wih = (const float*)d_in[3];
    const float* Whh = (const float*)d_in[4];
    const float* bih = (const float*)d_in[5];
    const float* bhh = (const float*)d_in[6];
    const float* g1w = (const float*)d_in[7];
    const float* g1b = (const float*)d_in[8];
    const float* g2w = (const float*)d_in[9];
    const float* g2b = (const float*)d_in[10];
    const float* fcw = (const float*)d_in[11];
    const float* fcb = (const float*)d_in[12];
    float* out = (float*)d_out;

    char* ws = (char*)d_ws;
    size_t off = 0;
    auto alloc = [&](size_t bytes) {
        char* p = ws + off;
        off = (off + bytes + 255) & ~(size_t)255;
        return p;
    };
    float* bufA = (float*)alloc((size_t)BN * NH * 4);  // 40.96 MB
    float* bufB = (float*)alloc((size_t)BN * NH * 4);  // 40.96 MB
    float* deg  = (float*)alloc(NN * 4);
    float* dinv = (float*)alloc(NN * 4);
    int*   cnt  = (int*)alloc(NN * 4);
    int*   fill = (int*)alloc(NN * 4);
    int*   rowp = (int*)alloc((NN + 1) * 4);
    int*   col  = (int*)alloc((size_t)NE * 4);
    float* val  = (float*)alloc((size_t)NE * 4);

    lstm_k<<<BN / 64, 256, 0, stream>>>(x, Wih, Whh, bih, bhh, bufA);

    init_k<<<(NN + 255) / 256, 256, 0, stream>>>(deg, cnt, fill);
    degacc_k<<<(NE + 255) / 256, 256, 0, stream>>>(ei, ew, deg, cnt);
    dinv_k<<<(NN + 255) / 256, 256, 0, stream>>>(deg, dinv);
    scan_k<<<1, 1024, 0, stream>>>(cnt, rowp);
    scatter_k<<<(NE + 255) / 256, 256, 0, stream>>>(ei, ew, dinv, rowp, fill, col, val);

    gemm_k<<<BN / 32, 256, 0, stream>>>(bufA, g1w, bufB);
    gather_k<<<BN / 4, 256, 0, stream>>>(bufB, rowp, col, val, dinv, g1b, bufA);
    gemm_k<<<BN / 32, 256, 0, stream>>>(bufA, g2w, bufB);
    gather_k<<<BN / 4, 256, 0, stream>>>(bufB, rowp, col, val, dinv, g2b, bufA);
    fc_k<<<BN / 16, 256, 0, stream>>>(bufA, fcw, fcb, out);
}

// Round 2
// 1417.930 us; speedup vs baseline: 2.9171x; 2.9171x over previous
//
#include <hip/hip_runtime.h>
#include <math.h>

#define NB 8
#define NN 10000
#define NT 12
#define ND 16
#define NH 128
#define NE 160000
#define BN (NB * NN)  // 80000

typedef __attribute__((ext_vector_type(8))) short short8v;
typedef __attribute__((ext_vector_type(4))) float f32x4;

__device__ __forceinline__ float sigmoidf_(float x) {
    return 1.0f / (1.0f + __expf(-x));
}
__device__ __forceinline__ float tanh_fast(float x) {
    x = fminf(15.0f, fmaxf(-15.0f, x));
    float t = __expf(-2.0f * x);
    return (1.0f - t) / (1.0f + t);
}
__device__ __forceinline__ unsigned short bf16_rn(float f) {
    unsigned int u = __float_as_uint(f);
    u += 0x7fffu + ((u >> 16) & 1u);
    return (unsigned short)(u >> 16);
}
__device__ __forceinline__ float bf16f(unsigned short s) {
    return __uint_as_float((unsigned int)s << 16);
}

// ---------- prep: split Whh/Wih into bf16 hi/lo (B-operand friendly) --------
__global__ void prep_w_k(const float* __restrict__ Whh, const float* __restrict__ Wih,
                         unsigned short* __restrict__ whh_hi, unsigned short* __restrict__ whh_lo,
                         unsigned short* __restrict__ wih_hi2, unsigned short* __restrict__ wih_lo2)
{
    int i = blockIdx.x * 256 + threadIdx.x;   // 65536 threads
    if (i < 512 * 128) {
        float w = Whh[i];
        unsigned short h = bf16_rn(w);
        whh_hi[i] = h;
        whh_lo[i] = bf16_rn(w - bf16f(h));
    }
    if (i < 512 * 16) {
        int row = i >> 4, d = i & 15;
        float w = Wih[i];
        unsigned short h = bf16_rn(w);
        unsigned short l = bf16_rn(w - bf16f(h));
        wih_hi2[row * 32 + d] = h;        // duplicated: pairs with [x_hi; x_lo]
        wih_hi2[row * 32 + 16 + d] = h;
        wih_lo2[row * 32 + d] = l;        // pairs with [x_hi; 0]
        wih_lo2[row * 32 + 16 + d] = 0;
    }
}

// ---------- prep: split x into bf16 hi/lo, A-fragment layout [seq][t][32] ---
__global__ void prep_x_k(const float* __restrict__ x, unsigned short* __restrict__ xp)
{
    long tid = (long)blockIdx.x * 256 + threadIdx.x;   // exactly BN*NT*4
    long row = tid >> 2;
    int q = (int)(tid & 3);
    float4 v = ((const float4*)(x + row * 16))[q];
    unsigned short h0 = bf16_rn(v.x), h1 = bf16_rn(v.y), h2 = bf16_rn(v.z), h3 = bf16_rn(v.w);
    ushort4 hi = make_ushort4(h0, h1, h2, h3);
    ushort4 lo = make_ushort4(bf16_rn(v.x - bf16f(h0)), bf16_rn(v.y - bf16f(h1)),
                              bf16_rn(v.z - bf16f(h2)), bf16_rn(v.w - bf16f(h3)));
    *(ushort4*)(xp + row * 32 + q * 4) = hi;
    *(ushort4*)(xp + row * 32 + 16 + q * 4) = lo;
}

// ---------- LSTM via split-bf16 MFMA ----------------------------------------
// block: 64 seqs, 512 threads (8 waves). wave w owns j-cols [w*16, w*16+16)
// of all 4 gates. h kept in LDS (bf16 hi/lo planes, XOR-swizzled), c in regs.
// z = h_hi*W_hi + h_lo*W_hi + h_hi*W_lo + x_hi*Wih_hi + x_lo*Wih_hi + x_hi*Wih_lo + bias
__global__ __launch_bounds__(512, 2) void lstm_mfma_k(
    const unsigned short* __restrict__ xp,
    const unsigned short* __restrict__ whh_hi, const unsigned short* __restrict__ whh_lo,
    const unsigned short* __restrict__ wih_hi2, const unsigned short* __restrict__ wih_lo2,
    const float* __restrict__ bih, const float* __restrict__ bhh,
    float* __restrict__ hout)
{
    __shared__ short hlds[2][64][128];   // 32 KB: [hi/lo][seq][j ^ ((seq&7)<<3)]
    const int tid = threadIdx.x;
    const int lane = tid & 63;
    const int wid = tid >> 6;        // 0..7
    const int j0 = wid * 16;
    const int l15 = lane & 15;
    const int lg = lane >> 4;        // 0..3 (k-group)
    const long seq0 = (long)blockIdx.x * 64;

    float bv[4];
#pragma unroll
    for (int g = 0; g < 4; ++g) {
        int rw = g * NH + j0 + l15;
        bv[g] = bih[rw] + bhh[rw];
    }

    f32x4 acc[4][4];  // [m-tile][gate]
    f32x4 c[4];
#pragma unroll
    for (int m = 0; m < 4; ++m) c[m] = (f32x4){0.f, 0.f, 0.f, 0.f};

    for (int t = 0; t < NT; ++t) {
#pragma unroll
        for (int m = 0; m < 4; ++m)
#pragma unroll
            for (int g = 0; g < 4; ++g)
                acc[m][g] = (f32x4){bv[g], bv[g], bv[g], bv[g]};

        // x A-fragments (issued early; consumed after the h-part)
        short8v xa[4];
#pragma unroll
        for (int m = 0; m < 4; ++m) {
            long seq = seq0 + m * 16 + l15;
            xa[m] = *(const short8v*)(xp + (seq * NT + t) * 32 + 8 * lg);
        }

        if (t > 0) {
#pragma unroll
            for (int kt = 0; kt < 4; ++kt) {
                short8v bh[4], bl[4];
#pragma unroll
                for (int g = 0; g < 4; ++g) {
                    int row = g * NH + j0 + l15;
                    bh[g] = *(const short8v*)(whh_hi + row * 128 + kt * 32 + 8 * lg);
                    bl[g] = *(const short8v*)(whh_lo + row * 128 + kt * 32 + 8 * lg);
                }
#pragma unroll
                for (int m = 0; m < 4; ++m) {
                    int seq = m * 16 + l15;
                    int k0 = (kt * 32 + 8 * lg) ^ ((seq & 7) << 3);
                    short8v ah = *(const short8v*)&hlds[0][seq][k0];
                    short8v al = *(const short8v*)&hlds[1][seq][k0];
#pragma unroll
                    for (int g = 0; g < 4; ++g)
                        acc[m][g] = __builtin_amdgcn_mfma_f32_16x16x32_bf16(ah, bh[g], acc[m][g], 0, 0, 0);
#pragma unroll
                    for (int g = 0; g < 4; ++g)
                        acc[m][g] = __builtin_amdgcn_mfma_f32_16x16x32_bf16(al, bh[g], acc[m][g], 0, 0, 0);
#pragma unroll
                    for (int g = 0; g < 4; ++g)
                        acc[m][g] = __builtin_amdgcn_mfma_f32_16x16x32_bf16(ah, bl[g], acc[m][g], 0, 0, 0);
                }
            }
        }
        // x part: A=[x_hi;x_lo] with B=[Wih_hi;Wih_hi], then A same with B=[Wih_lo;0]
#pragma unroll
        for (int g = 0; g < 4; ++g) {
            int row = g * NH + j0 + l15;
            short8v b1 = *(const short8v*)(wih_hi2 + row * 32 + 8 * lg);
            short8v b2 = *(const short8v*)(wih_lo2 + row * 32 + 8 * lg);
#pragma unroll
            for (int m = 0; m < 4; ++m)
                acc[m][g] = __builtin_amdgcn_mfma_f32_16x16x32_bf16(xa[m], b1, acc[m][g], 0, 0, 0);
#pragma unroll
            for (int m = 0; m < 4; ++m)
                acc[m][g] = __builtin_amdgcn_mfma_f32_16x16x32_bf16(xa[m], b2, acc[m][g], 0, 0, 0);
        }

        __syncthreads();   // all LDS h reads of this step complete

        // epilogue: gates -> c,h ; write h (bf16 hi/lo) back in place
#pragma unroll
        for (int m = 0; m < 4; ++m) {
#pragma unroll
            for (int r = 0; r < 4; ++r) {
                float zi = acc[m][0][r], zf = acc[m][1][r];
                float zg = acc[m][2][r], zo = acc[m][3][r];
                float iv = sigmoidf_(zi);
                float fv = sigmoidf_(zf);
                float gv = tanh_fast(zg);
                float ov = sigmoidf_(zo);
                float cc = fv * c[m][r] + iv * gv;
                c[m][r] = cc;
                float hv = ov * tanh_fast(cc);
                int seq = m * 16 + 4 * lg + r;
                int j = j0 + l15;
                if (t < NT - 1) {
                    unsigned short hh = bf16_rn(hv);
                    unsigned short hl = bf16_rn(hv - bf16f(hh));
                    int jj = j ^ ((seq & 7) << 3);
                    hlds[0][seq][jj] = (short)hh;
                    hlds[1][seq][jj] = (short)hl;
                } else {
                    hout[(seq0 + seq) * NH + j] = hv;
                }
            }
        }
        __syncthreads();   // h writes visible before next step's reads
    }
}

// ---------------- degree / CSR build ----------------------------------------
__global__ void init_k(float* deg, int* cnt, int* fill) {
    int n = blockIdx.x * 256 + threadIdx.x;
    if (n < NN) { deg[n] = 1.0f; cnt[n] = 0; fill[n] = 0; }  // 1.0 = self-loop
}

__global__ void degacc_k(const int* __restrict__ ei, const float* __restrict__ ew,
                         float* deg, int* cnt) {
    int e = blockIdx.x * 256 + threadIdx.x;
    if (e < NE) {
        int d = ei[NE + e];
        atomicAdd(&deg[d], ew[e]);
        atomicAdd(&cnt[d], 1);
    }
}

__global__ void dinv_k(const float* __restrict__ deg, float* dinv) {
    int n = blockIdx.x * 256 + threadIdx.x;
    if (n < NN) { float d = deg[n]; dinv[n] = d > 0.0f ? 1.0f / sqrtf(d) : 0.0f; }
}

__global__ __launch_bounds__(1024) void scan_k(const int* __restrict__ cnt,
                                               int* __restrict__ rowp) {
    __shared__ int sA[1024];
    __shared__ int sB[1024];
    const int tid = threadIdx.x;
    const int CH = 10;
    int base = tid * CH;
    int local[CH];
    int ssum = 0;
#pragma unroll
    for (int i = 0; i < CH; ++i) {
        int idx = base + i;
        int v = (idx < NN) ? cnt[idx] : 0;
        local[i] = v; ssum += v;
    }
    int* src = sA; int* dst = sB;
    src[tid] = ssum;
    __syncthreads();
    for (int off = 1; off < 1024; off <<= 1) {
        int v = src[tid];
        if (tid >= off) v += src[tid - off];
        dst[tid] = v;
        __syncthreads();
        int* tmp = src; src = dst; dst = tmp;
    }
    int run = src[tid] - ssum;
#pragma unroll
    for (int i = 0; i < CH; ++i) {
        int idx = base + i;
        if (idx < NN) rowp[idx] = run;
        run += local[i];
    }
    if (tid == 1023) rowp[NN] = src[1023];
}

__global__ void scatter_k(const int* __restrict__ ei, const float* __restrict__ ew,
                          const float* __restrict__ dinv, const int* __restrict__ rowp,
                          int* fill, int* __restrict__ col, float* __restrict__ val)
{
    int e = blockIdx.x * 256 + threadIdx.x;
    if (e >= NE) return;
    int srcn = ei[e], d = ei[NE + e];
    int pos = rowp[d] + atomicAdd(&fill[d], 1);
    col[pos] = srcn;
    val[pos] = dinv[srcn] * ew[e] * dinv[d];
}

// ---------------- xl = h @ W^T  (W: (128,128) row-major) --------------------
__global__ __launch_bounds__(256) void gemm_k(const float* __restrict__ in,
                                              const float* __restrict__ W,
                                              float* __restrict__ out)
{
    __shared__ float Wl[128 * 132];
    __shared__ float hl[8][132];
    const int tid = threadIdx.x;
    for (int l = tid; l < 128 * 32; l += 256) {
        int j = l >> 5, k4 = l & 31;
        float4 w4 = ((const float4*)W)[l];
        *(float4*)&Wl[j * 132 + k4 * 4] = w4;
    }
    const int rl = tid >> 5;
    const int jg = tid & 31;
    for (int it = 0; it < 4; ++it) {
        const long row0 = (long)blockIdx.x * 32 + it * 8;
        __syncthreads();
        for (int l = tid; l < 8 * 32; l += 256) {
            int r = l >> 5, k4 = l & 31;
            *(float4*)&hl[r][k4 * 4] = ((const float4*)(in + (row0 + r) * NH))[k4];
        }
        __syncthreads();
        float a0 = 0, a1 = 0, a2 = 0, a3 = 0;
#pragma unroll 4
        for (int k4 = 0; k4 < 32; ++k4) {
            float4 hv = *(const float4*)&hl[rl][k4 * 4];
            float4 w0 = *(const float4*)&Wl[(jg) * 132 + k4 * 4];
            float4 w1 = *(const float4*)&Wl[(jg + 32) * 132 + k4 * 4];
            float4 w2 = *(const float4*)&Wl[(jg + 64) * 132 + k4 * 4];
            float4 w3 = *(const float4*)&Wl[(jg + 96) * 132 + k4 * 4];
            a0 = fmaf(w0.x, hv.x, a0); a0 = fmaf(w0.y, hv.y, a0);
            a0 = fmaf(w0.z, hv.z, a0); a0 = fmaf(w0.w, hv.w, a0);
            a1 = fmaf(w1.x, hv.x, a1); a1 = fmaf(w1.y, hv.y, a1);
            a1 = fmaf(w1.z, hv.z, a1); a1 = fmaf(w1.w, hv.w, a1);
            a2 = fmaf(w2.x, hv.x, a2); a2 = fmaf(w2.y, hv.y, a2);
            a2 = fmaf(w2.z, hv.z, a2); a2 = fmaf(w2.w, hv.w, a2);
            a3 = fmaf(w3.x, hv.x, a3); a3 = fmaf(w3.y, hv.y, a3);
            a3 = fmaf(w3.z, hv.z, a3); a3 = fmaf(w3.w, hv.w, a3);
        }
        float* orow = out + (row0 + rl) * NH;
        orow[jg] = a0; orow[jg + 32] = a1; orow[jg + 64] = a2; orow[jg + 96] = a3;
    }
}

// ---------------- gather-aggregate + bias + relu (one wave per (b,dst)) -----
__global__ __launch_bounds__(256) void gather_k(const float* __restrict__ xl,
    const int* __restrict__ rowp, const int* __restrict__ col,
    const float* __restrict__ val, const float* __restrict__ dinv,
    const float* __restrict__ bias, float* __restrict__ out)
{
    const int lane = threadIdx.x & 63;
    const int wv = threadIdx.x >> 6;
    const int p = blockIdx.x * 4 + wv;
    const int b = p / NN;
    const int n = p - b * NN;
    const float* __restrict__ xb = xl + (long)b * NN * NH;
    const float dn = dinv[n];
    float2 acc = ((const float2*)(xb + (long)n * NH))[lane];
    const float sn = dn * dn;
    acc.x *= sn; acc.y *= sn;
    const int e1 = rowp[n + 1];
    for (int e = rowp[n]; e < e1; ++e) {
        const int sidx = col[e];
        const float w = val[e];
        const float2 u = ((const float2*)(xb + (long)sidx * NH))[lane];
        acc.x = fmaf(w, u.x, acc.x);
        acc.y = fmaf(w, u.y, acc.y);
    }
    const float bx = bias[2 * lane], by = bias[2 * lane + 1];
    const float ox = fmaxf(acc.x + bx, 0.0f);
    const float oy = fmaxf(acc.y + by, 0.0f);
    ((float2*)(out + (long)p * NH))[lane] = make_float2(ox, oy);
}

// ---------------- final FC: 128 -> 16 ---------------------------------------
__global__ __launch_bounds__(256) void fc_k(const float* __restrict__ h,
    const float* __restrict__ fw, const float* __restrict__ fb,
    float* __restrict__ out)
{
    __shared__ float wl[16][129];
    __shared__ float hl[16][129];
    const int tid = threadIdx.x;
    for (int l = tid; l < 16 * 128; l += 256) wl[l >> 7][l & 127] = fw[l];
    const long r0 = (long)blockIdx.x * 16;
    for (int l = tid; l < 16 * 128; l += 256) hl[l >> 7][l & 127] = h[r0 * NH + l];
    __syncthreads();
    const int rl = tid >> 4, o = tid & 15;
    float acc = fb[o];
#pragma unroll 8
    for (int k = 0; k < NH; ++k) acc = fmaf(hl[rl][k], wl[o][k], acc);
    out[(r0 + rl) * 16 + o] = acc;
}

// ---------------------------------------------------------------------------
extern "C" void kernel_launch(void* const* d_in, const int* in_sizes, int n_in,
                              void* d_out, int out_size, void* d_ws, size_t ws_size,
                              hipStream_t stream)
{
    const float* x   = (const float*)d_in[0];
    const int*   ei  = (const int*)d_in[1];
    const float* ew  = (const float*)d_in[2];
    const float* Wih = (const float*)d_in[3];
    const float* Whh = (const float*)d_in[4];
    const float* bih = (const float*)d_in[5];
    const float* bhh = (const float*)d_in[6];
    const float* g1w = (const float*)d_in[7];
    const float* g1b = (const float*)d_in[8];
    const float* g2w = (const float*)d_in[9];
    const float* g2b = (const float*)d_in[10];
    const float* fcw = (const float*)d_in[11];
    const float* fcb = (const float*)d_in[12];
    float* out = (float*)d_out;

    // workspace layout (xprep aliases bufB+CSR: xprep dead before they're written)
    char* ws = (char*)d_ws;
    float* bufA = (float*)ws;                                 // 40,960,000 B
    char* r2 = ws + (size_t)40960000;
    unsigned short* xprep = (unsigned short*)r2;              // 61,440,000 B
    float* bufB = (float*)r2;                                 // 40,960,000 B (alias)
    char* cq = r2 + (size_t)40960000;
    float* deg  = (float*)(cq + 0);
    float* dinv = (float*)(cq + 40192);
    int*   cnt  = (int*)(cq + 80384);
    int*   fill = (int*)(cq + 120576);
    int*   rowp = (int*)(cq + 160768);
    int*   col  = (int*)(cq + 200960);
    float* val  = (float*)(cq + 840960);
    char* wp = ws + (size_t)102400000;
    unsigned short* whh_hi  = (unsigned short*)(wp);
    unsigned short* whh_lo  = (unsigned short*)(wp + 131072);
    unsigned short* wih_hi2 = (unsigned short*)(wp + 262144);
    unsigned short* wih_lo2 = (unsigned short*)(wp + 294912);

    prep_w_k<<<256, 256, 0, stream>>>(Whh, Wih, whh_hi, whh_lo, wih_hi2, wih_lo2);
    prep_x_k<<<15000, 256, 0, stream>>>(x, xprep);
    lstm_mfma_k<<<BN / 64, 512, 0, stream>>>(xprep, whh_hi, whh_lo, wih_hi2, wih_lo2,
                                             bih, bhh, bufA);

    init_k<<<(NN + 255) / 256, 256, 0, stream>>>(deg, cnt, fill);
    degacc_k<<<(NE + 255) / 256, 256, 0, stream>>>(ei, ew, deg, cnt);
    dinv_k<<<(NN + 255) / 256, 256, 0, stream>>>(deg, dinv);
    scan_k<<<1, 1024, 0, stream>>>(cnt, rowp);
    scatter_k<<<(NE + 255) / 256, 256, 0, stream>>>(ei, ew, dinv, rowp, fill, col, val);

    gemm_k<<<BN / 32, 256, 0, stream>>>(bufA, g1w, bufB);
    gather_k<<<BN / 4, 256, 0, stream>>>(bufB, rowp, col, val, dinv, g1b, bufA);
    gemm_k<<<BN / 32, 256, 0, stream>>>(bufA, g2w, bufB);
    gather_k<<<BN / 4, 256, 0, stream>>>(bufB, rowp, col, val, dinv, g2b, bufA);
    fc_k<<<BN / 16, 256, 0, stream>>>(bufA, fcw, fcb, out);
}

// Round 3
// 1143.587 us; speedup vs baseline: 3.6169x; 1.2399x over previous
//
#include <hip/hip_runtime.h>
#include <math.h>

#define NB 8
#define NN 10000
#define NT 12
#define ND 16
#define NH 128
#define NE 160000
#define BN (NB * NN)  // 80000

typedef __attribute__((ext_vector_type(8))) short short8v;
typedef __attribute__((ext_vector_type(4))) float f32x4;
typedef unsigned short u16;

__device__ __forceinline__ float sigmoidf_(float x) {
    return 1.0f / (1.0f + __expf(-x));
}
__device__ __forceinline__ float tanh_fast(float x) {
    x = fminf(15.0f, fmaxf(-15.0f, x));
    float t = __expf(-2.0f * x);
    return (1.0f - t) / (1.0f + t);
}
__device__ __forceinline__ u16 bf16_rn(float f) {
    unsigned int u = __float_as_uint(f);
    u += 0x7fffu + ((u >> 16) & 1u);
    return (u16)(u >> 16);
}
__device__ __forceinline__ float bf16f(u16 s) {
    return __uint_as_float((unsigned int)s << 16);
}

// ---------- prep: split all weights into bf16 hi/lo -------------------------
__global__ void prep_w_k(const float* __restrict__ Whh, const float* __restrict__ Wih,
                         const float* __restrict__ g1w, const float* __restrict__ g2w,
                         u16* __restrict__ whh_hi, u16* __restrict__ whh_lo,
                         u16* __restrict__ wih_hi2, u16* __restrict__ wih_lo2,
                         u16* __restrict__ g1hi, u16* __restrict__ g1lo,
                         u16* __restrict__ g2hi, u16* __restrict__ g2lo)
{
    int i = blockIdx.x * 256 + threadIdx.x;   // 65536 threads
    if (i < 512 * 128) {
        float w = Whh[i];
        u16 h = bf16_rn(w);
        whh_hi[i] = h;
        whh_lo[i] = bf16_rn(w - bf16f(h));
    }
    if (i < 512 * 16) {
        int row = i >> 4, d = i & 15;
        float w = Wih[i];
        u16 h = bf16_rn(w);
        u16 l = bf16_rn(w - bf16f(h));
        wih_hi2[row * 32 + d] = h;        // pairs with [x_hi; x_lo]
        wih_hi2[row * 32 + 16 + d] = h;
        wih_lo2[row * 32 + d] = l;        // pairs with [x_hi; 0]
        wih_lo2[row * 32 + 16 + d] = 0;
    }
    if (i < 128 * 128) {
        float w1 = g1w[i];
        u16 h1 = bf16_rn(w1);
        g1hi[i] = h1; g1lo[i] = bf16_rn(w1 - bf16f(h1));
        float w2 = g2w[i];
        u16 h2 = bf16_rn(w2);
        g2hi[i] = h2; g2lo[i] = bf16_rn(w2 - bf16f(h2));
    }
}

// ---------- LSTM v2: B in registers, 1 barrier/step, double-buffered h ------
// 512 thr (8 waves), 64 seqs/block. wave w owns j-cols [16w,16w+16) of all 4
// gates. Whh hi/lo fragments live in VGPRs for the whole kernel.
__global__ __launch_bounds__(512, 2) void lstm2_k(
    const float* __restrict__ x,
    const u16* __restrict__ whh_hi, const u16* __restrict__ whh_lo,
    const u16* __restrict__ wih_hi2, const u16* __restrict__ wih_lo2,
    const float* __restrict__ bih, const float* __restrict__ bhh,
    u16* __restrict__ hhi_g, u16* __restrict__ hlo_g)
{
    __shared__ u16 Hhi[2][64][128];   // 32 KB
    __shared__ u16 Hlo[2][64][128];   // 32 KB
    const int tid = threadIdx.x;
    const int lane = tid & 63;
    const int wid = tid >> 6;
    const int j0 = wid * 16;
    const int l15 = lane & 15;
    const int lg = lane >> 4;          // 0..3
    const long seq0 = (long)blockIdx.x * 64;
    const int swzr = (l15 & 7) << 3;   // read-side XOR swizzle
    const int hilo = (lg < 2);         // this lane builds hi (1) or lo (0) x-frags

    // --- hoist all B fragments into registers ---
    short8v Bh[4][4], Bl[4][4];        // [kt][gate] : 128 VGPR
    short8v b1[4], b2[4];              // Wih       : 32 VGPR
    float bv[4];
#pragma unroll
    for (int kt = 0; kt < 4; ++kt)
#pragma unroll
        for (int g = 0; g < 4; ++g) {
            int row = g * NH + j0 + l15;
            Bh[kt][g] = *(const short8v*)(whh_hi + row * NH + kt * 32 + 8 * lg);
            Bl[kt][g] = *(const short8v*)(whh_lo + row * NH + kt * 32 + 8 * lg);
        }
#pragma unroll
    for (int g = 0; g < 4; ++g) {
        int row = g * NH + j0 + l15;
        b1[g] = *(const short8v*)(wih_hi2 + row * 32 + 8 * lg);
        b2[g] = *(const short8v*)(wih_lo2 + row * 32 + 8 * lg);
        bv[g] = bih[row] + bhh[row];
    }

    f32x4 c[4];
#pragma unroll
    for (int m = 0; m < 4; ++m) c[m] = (f32x4){0.f, 0.f, 0.f, 0.f};

    for (int t = 0; t < NT; ++t) {
        const int cur = t & 1, nxt = cur ^ 1;
#pragma unroll
        for (int m = 0; m < 4; ++m) {
            // x A-fragment built in-register (hi for lg<2, lo for lg>=2)
            const float* xb = x + ((seq0 + m * 16 + l15) * NT + t) * ND + (lg & 1) * 8;
            float4 v0 = *(const float4*)xb;
            float4 v1 = *(const float4*)(xb + 4);
            short8v xa;
            {
                float e0 = v0.x, e1 = v0.y, e2 = v0.z, e3 = v0.w;
                float e4 = v1.x, e5 = v1.y, e6 = v1.z, e7 = v1.w;
                u16 h, l;
                h = bf16_rn(e0); l = bf16_rn(e0 - bf16f(h)); xa[0] = (short)(hilo ? h : l);
                h = bf16_rn(e1); l = bf16_rn(e1 - bf16f(h)); xa[1] = (short)(hilo ? h : l);
                h = bf16_rn(e2); l = bf16_rn(e2 - bf16f(h)); xa[2] = (short)(hilo ? h : l);
                h = bf16_rn(e3); l = bf16_rn(e3 - bf16f(h)); xa[3] = (short)(hilo ? h : l);
                h = bf16_rn(e4); l = bf16_rn(e4 - bf16f(h)); xa[4] = (short)(hilo ? h : l);
                h = bf16_rn(e5); l = bf16_rn(e5 - bf16f(h)); xa[5] = (short)(hilo ? h : l);
                h = bf16_rn(e6); l = bf16_rn(e6 - bf16f(h)); xa[6] = (short)(hilo ? h : l);
                h = bf16_rn(e7); l = bf16_rn(e7 - bf16f(h)); xa[7] = (short)(hilo ? h : l);
            }

            f32x4 acc[4];
#pragma unroll
            for (int g = 0; g < 4; ++g)
                acc[g] = (f32x4){bv[g], bv[g], bv[g], bv[g]};

            if (t > 0) {
                const int sq = m * 16 + l15;
#pragma unroll
                for (int kt = 0; kt < 4; ++kt) {
                    const int kk = (kt * 32 + 8 * lg) ^ swzr;
                    short8v ah = *(const short8v*)&Hhi[cur][sq][kk];
                    short8v al = *(const short8v*)&Hlo[cur][sq][kk];
#pragma unroll
                    for (int g = 0; g < 4; ++g)
                        acc[g] = __builtin_amdgcn_mfma_f32_16x16x32_bf16(ah, Bh[kt][g], acc[g], 0, 0, 0);
#pragma unroll
                    for (int g = 0; g < 4; ++g)
                        acc[g] = __builtin_amdgcn_mfma_f32_16x16x32_bf16(al, Bh[kt][g], acc[g], 0, 0, 0);
#pragma unroll
                    for (int g = 0; g < 4; ++g)
                        acc[g] = __builtin_amdgcn_mfma_f32_16x16x32_bf16(ah, Bl[kt][g], acc[g], 0, 0, 0);
                }
            }
#pragma unroll
            for (int g = 0; g < 4; ++g)
                acc[g] = __builtin_amdgcn_mfma_f32_16x16x32_bf16(xa, b1[g], acc[g], 0, 0, 0);
#pragma unroll
            for (int g = 0; g < 4; ++g)
                acc[g] = __builtin_amdgcn_mfma_f32_16x16x32_bf16(xa, b2[g], acc[g], 0, 0, 0);

            // epilogue for this m-tile (overlaps next m's MFMAs across waves)
#pragma unroll
            for (int r = 0; r < 4; ++r) {
                float iv = sigmoidf_(acc[0][r]);
                float fv = sigmoidf_(acc[1][r]);
                float gv = tanh_fast(acc[2][r]);
                float ov = sigmoidf_(acc[3][r]);
                float cc = fv * c[m][r] + iv * gv;
                c[m][r] = cc;
                float hv = ov * tanh_fast(cc);
                int sq2 = m * 16 + 4 * lg + r;
                int j = j0 + l15;
                u16 hh = bf16_rn(hv);
                u16 hl2 = bf16_rn(hv - bf16f(hh));
                if (t < NT - 1) {
                    int jj = j ^ ((sq2 & 7) << 3);
                    Hhi[nxt][sq2][jj] = hh;
                    Hlo[nxt][sq2][jj] = hl2;
                } else {
                    long gidx = (seq0 + sq2) * NH + j;
                    hhi_g[gidx] = hh;
                    hlo_g[gidx] = hl2;
                }
            }
        }
        __syncthreads();   // single barrier: nxt-buffer writes visible
    }
}

// ---------- GCN GEMM: out = A @ W^T via split-bf16 MFMA, B in regs ----------
__global__ __launch_bounds__(512) void gemmx_k(
    const u16* __restrict__ Ahi, const u16* __restrict__ Alo,
    const u16* __restrict__ Whi, const u16* __restrict__ Wlo,
    float* __restrict__ out)
{
    const int tid = threadIdx.x;
    const int lane = tid & 63;
    const int wid = tid >> 6;
    const int j0 = wid * 16;
    const int l15 = lane & 15;
    const int lg = lane >> 4;
    const long row0 = (long)blockIdx.x * 64;

    short8v Bh[4], Bl[4];
#pragma unroll
    for (int kt = 0; kt < 4; ++kt) {
        Bh[kt] = *(const short8v*)(Whi + (j0 + l15) * NH + kt * 32 + 8 * lg);
        Bl[kt] = *(const short8v*)(Wlo + (j0 + l15) * NH + kt * 32 + 8 * lg);
    }
#pragma unroll
    for (int m = 0; m < 4; ++m) {
        f32x4 acc = (f32x4){0.f, 0.f, 0.f, 0.f};
#pragma unroll
        for (int kt = 0; kt < 4; ++kt) {
            long ar = (row0 + m * 16 + l15) * NH + kt * 32 + 8 * lg;
            short8v ah = *(const short8v*)(Ahi + ar);
            short8v al = *(const short8v*)(Alo + ar);
            acc = __builtin_amdgcn_mfma_f32_16x16x32_bf16(ah, Bh[kt], acc, 0, 0, 0);
            acc = __builtin_amdgcn_mfma_f32_16x16x32_bf16(al, Bh[kt], acc, 0, 0, 0);
            acc = __builtin_amdgcn_mfma_f32_16x16x32_bf16(ah, Bl[kt], acc, 0, 0, 0);
        }
#pragma unroll
        for (int r = 0; r < 4; ++r)
            out[(row0 + m * 16 + 4 * lg + r) * NH + j0 + l15] = acc[r];
    }
}

// ---------------- degree / CSR build ----------------------------------------
__global__ void init_k(float* deg, int* cnt, int* fill) {
    int n = blockIdx.x * 256 + threadIdx.x;
    if (n < NN) { deg[n] = 1.0f; cnt[n] = 0; fill[n] = 0; }
}

__global__ void degacc_k(const int* __restrict__ ei, const float* __restrict__ ew,
                         float* deg, int* cnt) {
    int e = blockIdx.x * 256 + threadIdx.x;
    if (e < NE) {
        int d = ei[NE + e];
        atomicAdd(&deg[d], ew[e]);
        atomicAdd(&cnt[d], 1);
    }
}

__global__ void dinv_k(const float* __restrict__ deg, float* dinv) {
    int n = blockIdx.x * 256 + threadIdx.x;
    if (n < NN) { float d = deg[n]; dinv[n] = d > 0.0f ? 1.0f / sqrtf(d) : 0.0f; }
}

__global__ __launch_bounds__(1024) void scan_k(const int* __restrict__ cnt,
                                               int* __restrict__ rowp) {
    __shared__ int sA[1024];
    __shared__ int sB[1024];
    const int tid = threadIdx.x;
    const int CH = 10;
    int base = tid * CH;
    int local[CH];
    int ssum = 0;
#pragma unroll
    for (int i = 0; i < CH; ++i) {
        int idx = base + i;
        int v = (idx < NN) ? cnt[idx] : 0;
        local[i] = v; ssum += v;
    }
    int* src = sA; int* dst = sB;
    src[tid] = ssum;
    __syncthreads();
    for (int off = 1; off < 1024; off <<= 1) {
        int v = src[tid];
        if (tid >= off) v += src[tid - off];
        dst[tid] = v;
        __syncthreads();
        int* tmp = src; src = dst; dst = tmp;
    }
    int run = src[tid] - ssum;
#pragma unroll
    for (int i = 0; i < CH; ++i) {
        int idx = base + i;
        if (idx < NN) rowp[idx] = run;
        run += local[i];
    }
    if (tid == 1023) rowp[NN] = src[1023];
}

__global__ void scatter_k(const int* __restrict__ ei, const float* __restrict__ ew,
                          const float* __restrict__ dinv, const int* __restrict__ rowp,
                          int* fill, int* __restrict__ col, float* __restrict__ val)
{
    int e = blockIdx.x * 256 + threadIdx.x;
    if (e >= NE) return;
    int srcn = ei[e], d = ei[NE + e];
    int pos = rowp[d] + atomicAdd(&fill[d], 1);
    col[pos] = srcn;
    val[pos] = dinv[srcn] * ew[e] * dinv[d];
}

// ---------- gather-aggregate + bias + relu; EMIT=0 -> bf16 planes, 1 -> f32 -
template<int EMIT>
__global__ __launch_bounds__(256) void gather_k(const float* __restrict__ xl,
    const int* __restrict__ rowp, const int* __restrict__ col,
    const float* __restrict__ val, const float* __restrict__ dinv,
    const float* __restrict__ bias,
    float* __restrict__ outf, u16* __restrict__ ohi, u16* __restrict__ olo)
{
    const int lane = threadIdx.x & 63;
    const int wv = threadIdx.x >> 6;
    const int p = blockIdx.x * 4 + wv;
    const int b = p / NN;
    const int n = p - b * NN;
    const float* __restrict__ xb = xl + (long)b * NN * NH;
    const float dn = dinv[n];
    float2 acc = ((const float2*)(xb + (long)n * NH))[lane];
    const float sn = dn * dn;
    acc.x *= sn; acc.y *= sn;
    const int e1 = rowp[n + 1];
    for (int e = rowp[n]; e < e1; ++e) {
        const int sidx = col[e];
        const float w = val[e];
        const float2 u = ((const float2*)(xb + (long)sidx * NH))[lane];
        acc.x = fmaf(w, u.x, acc.x);
        acc.y = fmaf(w, u.y, acc.y);
    }
    const float bx = bias[2 * lane], by = bias[2 * lane + 1];
    const float ox = fmaxf(acc.x + bx, 0.0f);
    const float oy = fmaxf(acc.y + by, 0.0f);
    if (EMIT == 0) {
        u16 hx = bf16_rn(ox), hy = bf16_rn(oy);
        u16 lx = bf16_rn(ox - bf16f(hx)), ly = bf16_rn(oy - bf16f(hy));
        ((ushort2*)(ohi + (long)p * NH))[lane] = make_ushort2(hx, hy);
        ((ushort2*)(olo + (long)p * NH))[lane] = make_ushort2(lx, ly);
    } else {
        ((float2*)(outf + (long)p * NH))[lane] = make_float2(ox, oy);
    }
}

// ---------------- final FC: 128 -> 16 ---------------------------------------
__global__ __launch_bounds__(256) void fc_k(const float* __restrict__ h,
    const float* __restrict__ fw, const float* __restrict__ fb,
    float* __restrict__ out)
{
    __shared__ float wl[16][129];
    __shared__ float hl[16][129];
    const int tid = threadIdx.x;
    for (int l = tid; l < 16 * 128; l += 256) wl[l >> 7][l & 127] = fw[l];
    const long r0 = (long)blockIdx.x * 16;
    for (int l = tid; l < 16 * 128; l += 256) hl[l >> 7][l & 127] = h[r0 * NH + l];
    __syncthreads();
    const int rl = tid >> 4, o = tid & 15;
    float acc = fb[o];
#pragma unroll 8
    for (int k = 0; k < NH; ++k) acc = fmaf(hl[rl][k], wl[o][k], acc);
    out[(r0 + rl) * 16 + o] = acc;
}

// ---------------------------------------------------------------------------
extern "C" void kernel_launch(void* const* d_in, const int* in_sizes, int n_in,
                              void* d_out, int out_size, void* d_ws, size_t ws_size,
                              hipStream_t stream)
{
    const float* x   = (const float*)d_in[0];
    const int*   ei  = (const int*)d_in[1];
    const float* ew  = (const float*)d_in[2];
    const float* Wih = (const float*)d_in[3];
    const float* Whh = (const float*)d_in[4];
    const float* bih = (const float*)d_in[5];
    const float* bhh = (const float*)d_in[6];
    const float* g1w = (const float*)d_in[7];
    const float* g1b = (const float*)d_in[8];
    const float* g2w = (const float*)d_in[9];
    const float* g2b = (const float*)d_in[10];
    const float* fcw = (const float*)d_in[11];
    const float* fcb = (const float*)d_in[12];
    float* out = (float*)d_out;

    // workspace layout (~84 MB):
    //   [0, 41MB)   bf16 plane pair (hi at +0, lo at +20.48MB); also reused as
    //               gather1 output planes, then as gather2's f32 output.
    //   [41, 82MB)  xl f32 (gemm outputs)
    //   [82MB, ..)  CSR + weight splits
    char* ws = (char*)d_ws;
    u16* hhi = (u16*)ws;
    u16* hlo = (u16*)(ws + 20480000);
    float* planesF = (float*)ws;
    float* xl = (float*)(ws + 40960000);
    char* cq = ws + 81920000;
    float* deg  = (float*)(cq + 0);
    float* dinv = (float*)(cq + 40960);
    int*   cnt  = (int*)(cq + 81920);
    int*   fill = (int*)(cq + 122880);
    int*   rowp = (int*)(cq + 163840);
    int*   col  = (int*)(cq + 204800);
    float* val  = (float*)(cq + 844800);
    char* wp = cq + 1484800;
    u16* whh_hi  = (u16*)(wp);
    u16* whh_lo  = (u16*)(wp + 131072);
    u16* wih_hi2 = (u16*)(wp + 262144);
    u16* wih_lo2 = (u16*)(wp + 294912);
    u16* g1hi    = (u16*)(wp + 327680);
    u16* g1lo    = (u16*)(wp + 360448);
    u16* g2hi    = (u16*)(wp + 393216);
    u16* g2lo    = (u16*)(wp + 425984);

    prep_w_k<<<256, 256, 0, stream>>>(Whh, Wih, g1w, g2w, whh_hi, whh_lo,
                                      wih_hi2, wih_lo2, g1hi, g1lo, g2hi, g2lo);
    lstm2_k<<<BN / 64, 512, 0, stream>>>(x, whh_hi, whh_lo, wih_hi2, wih_lo2,
                                         bih, bhh, hhi, hlo);

    init_k<<<(NN + 255) / 256, 256, 0, stream>>>(deg, cnt, fill);
    degacc_k<<<(NE + 255) / 256, 256, 0, stream>>>(ei, ew, deg, cnt);
    dinv_k<<<(NN + 255) / 256, 256, 0, stream>>>(deg, dinv);
    scan_k<<<1, 1024, 0, stream>>>(cnt, rowp);
    scatter_k<<<(NE + 255) / 256, 256, 0, stream>>>(ei, ew, dinv, rowp, fill, col, val);

    gemmx_k<<<BN / 64, 512, 0, stream>>>(hhi, hlo, g1hi, g1lo, xl);
    gather_k<0><<<BN / 4, 256, 0, stream>>>(xl, rowp, col, val, dinv, g1b,
                                            nullptr, hhi, hlo);
    gemmx_k<<<BN / 64, 512, 0, stream>>>(hhi, hlo, g2hi, g2lo, xl);
    gather_k<1><<<BN / 4, 256, 0, stream>>>(xl, rowp, col, val, dinv, g2b,
                                            planesF, nullptr, nullptr);
    fc_k<<<BN / 16, 256, 0, stream>>>(planesF, fcw, fcb, out);
}